// Round 10
// baseline (125.562 us; speedup 1.0000x reference)
//
#include <hip/hip_runtime.h>

typedef float f32x4 __attribute__((ext_vector_type(4)));
typedef __bf16 bf16x8 __attribute__((ext_vector_type(8)));
typedef unsigned short u16;

__device__ __forceinline__ f32x4 mfma16(bf16x8 a, bf16x8 b, f32x4 c) {
  return __builtin_amdgcn_mfma_f32_16x16x32_bf16(a, b, c, 0, 0, 0);
}

__device__ __forceinline__ void gll16(const void* g, void* l) {
  __builtin_amdgcn_global_load_lds(
      (const __attribute__((address_space(1))) void*)g,
      (__attribute__((address_space(3))) void*)l, 16, 0, 0);
}

// ---------------- fused f32 -> bf16 convert (x, Wp, Wo -> contiguous ws) ----
__global__ void cvt3_kernel(const float* __restrict__ x,
                            const float* __restrict__ wp,
                            const float* __restrict__ wo,
                            __bf16* __restrict__ out) {
  int idx = blockIdx.x * blockDim.x + threadIdx.x;
  int stride = gridDim.x * blockDim.x;
  for (int i = idx; i < 1048576; i += stride) {  // 8.39M elems / 8
    const float* src;
    if (i < 524288) src = x + (size_t)i * 8;
    else if (i < 917504) src = wp + (size_t)(i - 524288) * 8;
    else src = wo + (size_t)(i - 917504) * 8;
    f32x4 a = *(const f32x4*)src;
    f32x4 b = *(const f32x4*)(src + 4);
    bf16x8 r;
#pragma unroll
    for (int j = 0; j < 4; ++j) {
      r[j] = (__bf16)a[j];
      r[4 + j] = (__bf16)b[j];
    }
    *(bf16x8*)(out + (size_t)i * 8) = r;
  }
}

// ---------------- 8-phase 256x256 bf16 GEMM (m201 template port) -----------
// C = A @ B^T + bias. 512 thr = 8 waves (2M x 4N), wave tile 128x64.
// BK=64, 2 LDS slots per operand (2 x 256x64 each, 128 KB total).
// st_16x32 swizzle: byte ^= ((byte>>9)&1)<<5 -> pre-swizzled global src
// (global_load_lds writes linearly) + swizzled ds_read.
// 4 phases per K-tile: {reads?; stage 1 half-tile; bar; lgkm0; SB0;
//  prio1; 16 MFMA quadrant; prio0; [vmcnt(4) at p3]; bar}.
// Stage stream 6 half-tiles ahead; all frag reads in p0/p1 => every
// overwrite is barrier-separated from its last read.
// MODE 0: f32 out. MODE 1: QKV pack (Q row-major; K/V fragment-linear).
template <int MODE>
__global__ __launch_bounds__(512, 2) void gemm8p(
    const u16* __restrict__ A, const u16* __restrict__ B,
    const float* __restrict__ bias, float* __restrict__ Cout,
    __bf16* __restrict__ qb, __bf16* __restrict__ kp, __bf16* __restrict__ vp,
    int M, int N, int K, int mtiles) {
  __shared__ u16 lA[2 * 256 * 64];  // 64 KB
  __shared__ u16 lB[2 * 256 * 64];  // 64 KB
  const int tid = threadIdx.x;   // 0..511
  const int wid = tid >> 6;      // 0..7
  const int lane = tid & 63;
  const int lr = lane & 15, lg = lane >> 4;

  // bijective XCD swizzle (gridDim.x % 8 == 0)
  const int nwg = gridDim.x;
  const int lid = blockIdx.x;
  const int sw = (lid & 7) * (nwg >> 3) + (lid >> 3);
  const int bm = (sw % mtiles) * 256;
  const int bn = (sw / mtiles) * 256;
  const int wm = (wid >> 2) * 128;  // 0 / 128
  const int wn = (wid & 3) * 64;    // 0..192

  f32x4 acc[8][4] = {};
  const int KT = K >> 6;   // K-tiles (16)
  const int NH = KT * 4;   // half-tiles (64)

  // stage half-tile id h: kt=h>>2, part: 0=A lo,1=A hi,2=B lo,3=B hi
  auto stageh = [&](int h) {
    const int kt = h >> 2, part = h & 3, slot = kt & 1;
    const int kk = kt << 6;
#pragma unroll
    for (int j = 0; j < 2; ++j) {
      int o16 = tid + j * 512;           // 16B chunk 0..1023
      int row = o16 >> 3;                // 0..127
      int scb = ((o16 & 7) * 16) ^ ((row & 4) << 3);  // pre-swizzled col byte
      if (part < 2)
        gll16(A + (size_t)(bm + (part << 7) + row) * K + kk + (scb >> 1),
              lA + slot * 16384 + (part << 13) + o16 * 8);
      else
        gll16(B + (size_t)(bn + ((part & 1) << 7) + row) * K + kk + (scb >> 1),
              lB + slot * 16384 + ((part & 1) << 13) + o16 * 8);
    }
  };

  bf16x8 af[8][2], bfr[4][2];
  auto rdA = [&](int slot, int mt, int ks) -> bf16x8 {
    int row = wm + mt * 16 + lr;
    int col = (ks * 32 + lg * 8) ^ ((row & 4) << 2);
    return *(const bf16x8*)&lA[slot * 16384 + row * 64 + col];
  };
  auto rdB = [&](int slot, int nt, int ks) -> bf16x8 {
    int row = wn + nt * 16 + lr;
    int col = (ks * 32 + lg * 8) ^ ((row & 4) << 2);
    return *(const bf16x8*)&lB[slot * 16384 + row * 64 + col];
  };
  auto quad = [&](int qm, int qn) {
#pragma unroll
    for (int mi = 0; mi < 4; ++mi)
#pragma unroll
      for (int ni = 0; ni < 2; ++ni)
#pragma unroll
        for (int ks = 0; ks < 2; ++ks) {
          int mt = qm * 4 + mi, nt = qn * 2 + ni;
          acc[mt][nt] = mfma16(af[mt][ks], bfr[nt][ks], acc[mt][nt]);
        }
  };

  // prologue: 6 half-tiles (kt0 complete + kt1 A-halves)
#pragma unroll
  for (int h = 0; h < 6; ++h) stageh(h);
  __builtin_amdgcn_sched_barrier(0);
  asm volatile("s_waitcnt vmcnt(4)" ::: "memory");  // kt0 done, 2 ht in flight
  __builtin_amdgcn_s_barrier();

  for (int kt = 0; kt < KT; ++kt) {
    const int slot = kt & 1;
    const int hb = kt * 4 + 6;
    // ---------- phase 0: A0-3 + B0-1 reads, quadrant (0,0) ----------
#pragma unroll
    for (int mt = 0; mt < 4; ++mt)
#pragma unroll
      for (int ks = 0; ks < 2; ++ks) af[mt][ks] = rdA(slot, mt, ks);
#pragma unroll
    for (int nt = 0; nt < 2; ++nt)
#pragma unroll
      for (int ks = 0; ks < 2; ++ks) bfr[nt][ks] = rdB(slot, nt, ks);
    if (hb < NH) stageh(hb);
    __builtin_amdgcn_sched_barrier(0);
    __builtin_amdgcn_s_barrier();
    asm volatile("s_waitcnt lgkmcnt(0)" ::: "memory");
    __builtin_amdgcn_sched_barrier(0);
    __builtin_amdgcn_s_setprio(1);
    quad(0, 0);
    __builtin_amdgcn_s_setprio(0);
    __builtin_amdgcn_sched_barrier(0);
    __builtin_amdgcn_s_barrier();
    // ---------- phase 1: A4-7 + B2-3 reads, quadrant (1,0) ----------
#pragma unroll
    for (int mt = 4; mt < 8; ++mt)
#pragma unroll
      for (int ks = 0; ks < 2; ++ks) af[mt][ks] = rdA(slot, mt, ks);
#pragma unroll
    for (int nt = 2; nt < 4; ++nt)
#pragma unroll
      for (int ks = 0; ks < 2; ++ks) bfr[nt][ks] = rdB(slot, nt, ks);
    if (hb + 1 < NH) stageh(hb + 1);
    __builtin_amdgcn_sched_barrier(0);
    __builtin_amdgcn_s_barrier();
    asm volatile("s_waitcnt lgkmcnt(0)" ::: "memory");
    __builtin_amdgcn_sched_barrier(0);
    __builtin_amdgcn_s_setprio(1);
    quad(1, 0);
    __builtin_amdgcn_s_setprio(0);
    __builtin_amdgcn_sched_barrier(0);
    __builtin_amdgcn_s_barrier();
    // ---------- phase 2: no reads, quadrant (0,1) ----------
    if (hb + 2 < NH) stageh(hb + 2);
    __builtin_amdgcn_sched_barrier(0);
    __builtin_amdgcn_s_barrier();
    __builtin_amdgcn_sched_barrier(0);
    __builtin_amdgcn_s_setprio(1);
    quad(0, 1);
    __builtin_amdgcn_s_setprio(0);
    __builtin_amdgcn_sched_barrier(0);
    __builtin_amdgcn_s_barrier();
    // ---------- phase 3: no reads, quadrant (1,1), counted vmcnt ----------
    if (hb + 3 < NH) stageh(hb + 3);
    __builtin_amdgcn_sched_barrier(0);
    __builtin_amdgcn_s_barrier();
    __builtin_amdgcn_sched_barrier(0);
    __builtin_amdgcn_s_setprio(1);
    quad(1, 1);
    __builtin_amdgcn_s_setprio(0);
    __builtin_amdgcn_sched_barrier(0);
    if (kt + 1 < KT) {
      if (4 * kt + 9 < NH)
        asm volatile("s_waitcnt vmcnt(4)" ::: "memory");
      else if (4 * kt + 8 < NH)
        asm volatile("s_waitcnt vmcnt(2)" ::: "memory");
      else
        asm volatile("s_waitcnt vmcnt(0)" ::: "memory");
    }
    __builtin_amdgcn_s_barrier();
  }

  // ---------------- epilogue ----------------
#pragma unroll
  for (int nt = 0; nt < 4; ++nt) {
    int col = bn + wn + nt * 16 + lr;
    float bv = bias[col];
#pragma unroll
    for (int mt = 0; mt < 8; ++mt) {
#pragma unroll
      for (int r = 0; r < 4; ++r) {
        int row = bm + wm + mt * 16 + lg * 4 + r;
        float val = acc[mt][nt][r] + bv;
        if (MODE == 0) {
          Cout[(size_t)row * N + col] = val;
        } else {
          __bf16 bx = (__bf16)val;
          int b = row >> 11, s = row & 2047;
          int third = col >> 10, hd = col & 1023;
          int h = hd >> 6, d = hd & 63;
          if (third == 0) {
            qb[(size_t)row * 1024 + hd] = bx;
          } else {
            int bh = b * 16 + h, t2 = s >> 6, sr = s & 63;
            size_t tb = ((size_t)(bh * 32 + t2)) * 4096;
            if (third == 1)
              kp[tb + (sr >> 4) * 1024 + (d >> 5) * 512 + ((d >> 3) & 3) * 128 +
                 (sr & 15) * 8 + (d & 7)] = bx;
            else
              vp[tb + (d >> 4) * 1024 + (sr >> 5) * 512 + ((sr >> 3) & 3) * 128 +
                 (d & 15) * 8 + (sr & 7)] = bx;
          }
        }
      }
    }
  }
}

// ---------------- old 2-phase pipelined GEMM (gemm2 only this round) -------
template <int BM, int BN, int MODE>
__global__ __launch_bounds__(256, 3) void gemm_bt(
    const u16* __restrict__ A, const u16* __restrict__ B,
    const float* __restrict__ bias, float* __restrict__ Cout,
    int M, int N, int K, int mtiles) {
  constexpr int MREP = BM / 32;
  constexpr int NREP = BN / 32;
  constexpr int LA = BM / 64;
  constexpr int LB = BN / 64;
  static_assert(LA + LB == 4, "vmcnt literals assume 4 loads/wave/step");
  __shared__ u16 lA[3 * BM * 32];
  __shared__ u16 lB[3 * BN * 32];
  const int tid = threadIdx.x;
  const int wid = tid >> 6;
  const int lane = tid & 63;
  const int lr = lane & 15;
  const int lg = lane >> 4;

  const int nwg = gridDim.x;
  const int lid = blockIdx.x;
  const int sw = (lid & 7) * (nwg >> 3) + (lid >> 3);
  const int bm = (sw % mtiles) * BM;
  const int bn = (sw / mtiles) * BN;
  const int wm = (wid >> 1) * (BM / 2);
  const int wn = (wid & 1) * (BN / 2);

  f32x4 acc[MREP][NREP] = {};

  auto stage = [&](int bf, int t) {
    const int kt = t * 32;
    char* baseA = (char*)lA + bf * (BM * 64);
    char* baseB = (char*)lB + bf * (BN * 64);
#pragma unroll
    for (int j = 0; j < LA; ++j) {
      int off = (tid + j * 256) * 16;
      gll16(A + (size_t)(bm + (off >> 6)) * K + kt + ((off & 63) >> 1),
            baseA + off);
    }
#pragma unroll
    for (int j = 0; j < LB; ++j) {
      int off = (tid + j * 256) * 16;
      gll16(B + (size_t)(bn + (off >> 6)) * K + kt + ((off & 63) >> 1),
            baseB + off);
    }
  };

  const int T = K / 32;
  stage(0, 0);
  stage(1, 1);
  stage(2, 2);

  for (int t = 0; t < T; ++t) {
    const int rem = T - 1 - t;
    if (rem >= 2)
      asm volatile("s_waitcnt vmcnt(8)" ::: "memory");
    else if (rem == 1)
      asm volatile("s_waitcnt vmcnt(4)" ::: "memory");
    else
      asm volatile("s_waitcnt vmcnt(0)" ::: "memory");
    __builtin_amdgcn_s_barrier();

    const u16* cA = lA + (t % 3) * BM * 32;
    const u16* cB = lB + (t % 3) * BN * 32;
    bf16x8 af[MREP], bfr[NREP];
#pragma unroll
    for (int mt = 0; mt < MREP; ++mt)
      af[mt] = *(const bf16x8*)&cA[(wm + mt * 16 + lr) * 32 + lg * 8];
#pragma unroll
    for (int nt = 0; nt < NREP; ++nt)
      bfr[nt] = *(const bf16x8*)&cB[(wn + nt * 16 + lr) * 32 + lg * 8];
#pragma unroll
    for (int mt = 0; mt < MREP; ++mt)
#pragma unroll
      for (int nt = 0; nt < NREP; ++nt)
        acc[mt][nt] = mfma16(af[mt], bfr[nt], acc[mt][nt]);

    __builtin_amdgcn_sched_barrier(0);
    __builtin_amdgcn_s_barrier();
    if (t + 3 < T) stage(t % 3, t + 3);
  }

#pragma unroll
  for (int nt = 0; nt < NREP; ++nt) {
    int col = bn + wn + nt * 16 + lr;
    float bv = bias[col];
#pragma unroll
    for (int mt = 0; mt < MREP; ++mt) {
#pragma unroll
      for (int r = 0; r < 4; ++r) {
        int row = bm + wm + mt * 16 + lg * 4 + r;
        Cout[(size_t)row * N + col] = acc[mt][nt][r] + bv;
      }
    }
  }
}

// ---------------- fused causal+ALiBi flash attention ----------------
__global__ __launch_bounds__(64, 4) void attn_kernel(
    const __bf16* __restrict__ qb, const __bf16* __restrict__ kp,
    const __bf16* __restrict__ vp, __bf16* __restrict__ aout) {
  __shared__ __bf16 p_lds[16][72];
  const int lane = threadIdx.x & 63;
  const int lr = lane & 15;
  const int lg = lane >> 4;

  const int lid = blockIdx.x;
  const int xcd = lid & 7;
  const int rest = lid >> 3;
  const int bh = xcd * 4 + (rest & 3);
  const int a16 = 127 - (rest >> 2);
  const int b = bh >> 4, h = bh & 15;
  const int qr0 = a16 * 16;
  const int ntl = (a16 >> 2) + 1;

  const float LOG2E = 1.4426950408889634f;
  const float c1 = 0.125f * LOG2E;
  const float c2 = exp2f(-(float)(h + 1) * 0.5f) * LOG2E;

  bf16x8 ones;
#pragma unroll
  for (int j = 0; j < 8; ++j) ones[j] = (__bf16)1.0f;

  const u16* ktiles = (const u16*)kp + (size_t)bh * 32 * 4096;
  const u16* vtiles = (const u16*)vp + (size_t)bh * 32 * 4096;

  const __bf16* qrow = qb + (size_t)(b * 2048 + qr0 + lr) * 1024 + h * 64;
  bf16x8 qf0 = *(const bf16x8*)(qrow + lg * 8);
  bf16x8 qf1 = *(const bf16x8*)(qrow + 32 + lg * 8);

  float m[4], l[4], cq[4];
  f32x4 o[4];
#pragma unroll
  for (int r = 0; r < 4; ++r) {
    m[r] = 0.f;
    l[r] = 0.f;
    cq[r] = c2 * (float)(qr0 + lg * 4 + r);
  }
#pragma unroll
  for (int dt = 0; dt < 4; ++dt) o[dt] = (f32x4){0.f, 0.f, 0.f, 0.f};

  for (int t = 0; t < ntl; ++t) {
    const u16* kb = ktiles + (size_t)t * 4096;
    const u16* vb = vtiles + (size_t)t * 4096;
    const int kv = t * 64;
    const bool last = (t == ntl - 1);

    bf16x8 ka[8], va[8];
#pragma unroll
    for (int j = 0; j < 8; ++j)
      ka[j] = *(const bf16x8*)(kb + j * 512 + lane * 8);
#pragma unroll
    for (int j = 0; j < 8; ++j)
      va[j] = *(const bf16x8*)(vb + j * 512 + lane * 8);

    f32x4 s[4];
#pragma unroll
    for (int nt = 0; nt < 4; ++nt) {
      f32x4 tt = (f32x4){0.f, 0.f, 0.f, 0.f};
      tt = mfma16(qf0, ka[nt * 2], tt);
      tt = mfma16(qf1, ka[nt * 2 + 1], tt);
      s[nt] = tt;
    }

#pragma unroll
    for (int nt = 0; nt < 4; ++nt) {
      float bnt = c2 * (float)(kv + nt * 16 + lr);
#pragma unroll
      for (int r = 0; r < 4; ++r)
        s[nt][r] = __builtin_fmaf(s[nt][r], c1, bnt - cq[r]);
    }
    if (last) {
#pragma unroll
      for (int nt = 0; nt < 4; ++nt) {
        float kf = (float)(kv + nt * 16 + lr);
#pragma unroll
        for (int r = 0; r < 4; ++r) {
          float qi = (float)(qr0 + lg * 4 + r);
          if (kf > qi) s[nt][r] = -1e30f;
        }
      }
    }

    float pm[4];
#pragma unroll
    for (int r = 0; r < 4; ++r)
      pm[r] = fmaxf(fmaxf(s[0][r], s[1][r]), fmaxf(s[2][r], s[3][r]));
    bool ok = (pm[0] <= m[0] + 8.f) && (pm[1] <= m[1] + 8.f) &&
              (pm[2] <= m[2] + 8.f) && (pm[3] <= m[3] + 8.f);
    if (!__all(ok)) {
#pragma unroll
      for (int r = 0; r < 4; ++r)
#pragma unroll
        for (int d = 1; d < 16; d <<= 1)
          pm[r] = fmaxf(pm[r], __shfl_xor(pm[r], d));
#pragma unroll
      for (int r = 0; r < 4; ++r) {
        float mn = fmaxf(m[r], pm[r]);
        float fac = __builtin_amdgcn_exp2f(m[r] - mn);
        m[r] = mn;
        l[r] *= fac;
#pragma unroll
        for (int dt = 0; dt < 4; ++dt) o[dt][r] *= fac;
      }
    }

#pragma unroll
    for (int nt = 0; nt < 4; ++nt)
#pragma unroll
      for (int r = 0; r < 4; ++r) {
        float e = __builtin_amdgcn_exp2f(s[nt][r] - m[r]);
        p_lds[lg * 4 + r][nt * 16 + lr] = (__bf16)e;
      }

    bf16x8 pa0 = *(const bf16x8*)&p_lds[lr][lg * 8];
    bf16x8 pa1 = *(const bf16x8*)&p_lds[lr][32 + lg * 8];

    {
      f32x4 tt = (f32x4){0.f, 0.f, 0.f, 0.f};
      tt = mfma16(pa0, ones, tt);
      tt = mfma16(pa1, ones, tt);
#pragma unroll
      for (int r = 0; r < 4; ++r) l[r] += tt[r];
    }

#pragma unroll
    for (int dt = 0; dt < 4; ++dt) {
      o[dt] = mfma16(pa0, va[dt * 2], o[dt]);
      o[dt] = mfma16(pa1, va[dt * 2 + 1], o[dt]);
    }
  }

#pragma unroll
  for (int dt = 0; dt < 4; ++dt)
#pragma unroll
    for (int r = 0; r < 4; ++r) {
      float val = o[dt][r] / l[r];
      aout[(size_t)(b * 2048 + qr0 + lg * 4 + r) * 1024 + h * 64 + dt * 16 + lr] =
          (__bf16)val;
    }
}

extern "C" void kernel_launch(void* const* d_in, const int* in_sizes, int n_in,
                              void* d_out, int out_size, void* d_ws, size_t ws_size,
                              hipStream_t stream) {
  (void)in_sizes; (void)n_in; (void)out_size; (void)ws_size;
  const float* x = (const float*)d_in[0];
  const float* Wp = (const float*)d_in[1];
  const float* bp = (const float*)d_in[2];
  const float* Wo = (const float*)d_in[3];
  const float* bo = (const float*)d_in[4];
  float* out = (float*)d_out;

  char* ws = (char*)d_ws;
  u16* xb  = (u16*)(ws);                        // 8 MB  x bf16 [4096,1024]
  u16* wpb = (u16*)(ws + (size_t)(8u << 20));   // 6 MB  W_packed bf16
  u16* wob = (u16*)(ws + (size_t)(14u << 20));  // 2 MB  W_out bf16
  u16* qbp = (u16*)(ws + (size_t)(16u << 20));  // 8 MB  Q [4096,1024]
  u16* kpp = (u16*)(ws + (size_t)(24u << 20));  // 8 MB  K fragment tiles
  u16* vpp = (u16*)(ws + (size_t)(32u << 20));  // 8 MB  V fragment tiles
  u16* ab  = xb;  // attention output reuses x_bf16 space

  // xb/wpb/wob are contiguous: one fused convert
  cvt3_kernel<<<2048, 256, 0, stream>>>(x, Wp, Wo, (__bf16*)xb);
  // gemm1: 8-phase 256x256, grid 16x12 = 192 blocks (1/CU, 8 waves)
  gemm8p<1><<<192, 512, 0, stream>>>(
      xb, wpb, bp, nullptr, (__bf16*)qbp, (__bf16*)kpp, (__bf16*)vpp,
      4096, 3072, 1024, 16);
  attn_kernel<<<4096, 64, 0, stream>>>(
      (const __bf16*)qbp, (const __bf16*)kpp, (const __bf16*)vpp, (__bf16*)ab);
  // gemm2: old pipelined 128x128, grid 256
  gemm_bt<128, 128, 0><<<256, 256, 0, stream>>>(
      ab, wob, bo, out, 4096, 1024, 1024, 32);
}

// Round 11
// 114.993 us; speedup vs baseline: 1.0919x; 1.0919x over previous
//
#include <hip/hip_runtime.h>

typedef float f32x4 __attribute__((ext_vector_type(4)));
typedef __bf16 bf16x8 __attribute__((ext_vector_type(8)));
typedef unsigned short u16;

__device__ __forceinline__ f32x4 mfma16(bf16x8 a, bf16x8 b, f32x4 c) {
  return __builtin_amdgcn_mfma_f32_16x16x32_bf16(a, b, c, 0, 0, 0);
}

__device__ __forceinline__ void gll16(const void* g, void* l) {
  __builtin_amdgcn_global_load_lds(
      (const __attribute__((address_space(1))) void*)g,
      (__attribute__((address_space(3))) void*)l, 16, 0, 0);
}

// ---------------- fused f32 -> bf16 convert (x, Wp, Wo -> contiguous ws) ----
__global__ void cvt3_kernel(const float* __restrict__ x,
                            const float* __restrict__ wp,
                            const float* __restrict__ wo,
                            __bf16* __restrict__ out) {
  int idx = blockIdx.x * blockDim.x + threadIdx.x;
  int stride = gridDim.x * blockDim.x;
  for (int i = idx; i < 1048576; i += stride) {  // 8.39M elems / 8
    const float* src;
    if (i < 524288) src = x + (size_t)i * 8;
    else if (i < 917504) src = wp + (size_t)(i - 524288) * 8;
    else src = wo + (size_t)(i - 917504) * 8;
    f32x4 a = *(const f32x4*)src;
    f32x4 b = *(const f32x4*)(src + 4);
    bf16x8 r;
#pragma unroll
    for (int j = 0; j < 4; ++j) {
      r[j] = (__bf16)a[j];
      r[4 + j] = (__bf16)b[j];
    }
    *(bf16x8*)(out + (size_t)i * 8) = r;
  }
}

// ---------------- bf16 GEMM: C = A @ B^T + bias ----------------
// 3-deep counted-vmcnt pipeline (round-9 structure) + CORRECT 16B-chunk
// swizzle: LDS chunk16 i holds global chunk c = (i&3 - (row>>1))&3 where
// row = i>>2 (pre-permuted gll16 SOURCE; LDS dest linear). Fragment read at
// slot ((lg + (row>>1))&3) -> bank-group (4*row + slot) mod 8 covers all 8
// groups with 2 lanes each across 16 consecutive rows = conflict-free.
// 128x128, BK=32, 4 waves as 2x2, wave tile 64x64 (16 MFMA : 8 ds_read).
// MODE 0: f32 out. MODE 1: QKV pack (Q row-major; K/V fragment-linear).
template <int BM, int BN, int MODE>
__global__ __launch_bounds__(256, 3) void gemm_bt(
    const u16* __restrict__ A, const u16* __restrict__ B,
    const float* __restrict__ bias, float* __restrict__ Cout,
    __bf16* __restrict__ qb, __bf16* __restrict__ kp, __bf16* __restrict__ vp,
    int M, int N, int K, int mtiles) {
  constexpr int MREP = BM / 32;
  constexpr int NREP = BN / 32;
  constexpr int LA = BM / 64;
  constexpr int LB = BN / 64;
  static_assert(LA + LB == 4, "vmcnt literals assume 4 loads/wave/step");
  __shared__ u16 lA[3 * BM * 32];
  __shared__ u16 lB[3 * BN * 32];
  const int tid = threadIdx.x;
  const int wid = tid >> 6;
  const int lane = tid & 63;
  const int lr = lane & 15;
  const int lg = lane >> 4;

  // bijective XCD swizzle (gridDim.x % 8 == 0)
  const int nwg = gridDim.x;
  const int lid = blockIdx.x;
  const int sw = (lid & 7) * (nwg >> 3) + (lid >> 3);
  const int bm = (sw % mtiles) * BM;
  const int bn = (sw / mtiles) * BN;
  const int wm = (wid >> 1) * (BM / 2);
  const int wn = (wid & 1) * (BN / 2);

  f32x4 acc[MREP][NREP] = {};

  // stage: LDS dest linear in tid; SOURCE chunk permuted (inverse swizzle)
  auto stage = [&](int bf, int t) {
    const int kt = t * 32;
    char* baseA = (char*)lA + bf * (BM * 64);
    char* baseB = (char*)lB + bf * (BN * 64);
#pragma unroll
    for (int j = 0; j < LA; ++j) {
      int i16 = tid + j * 256;              // chunk16 index 0..BM*4-1
      int row = i16 >> 2;
      int c = ((i16 & 3) - (row >> 1)) & 3;  // global chunk stored here
      gll16(A + (size_t)(bm + row) * K + kt + c * 8, baseA + i16 * 16);
    }
#pragma unroll
    for (int j = 0; j < LB; ++j) {
      int i16 = tid + j * 256;
      int row = i16 >> 2;
      int c = ((i16 & 3) - (row >> 1)) & 3;
      gll16(B + (size_t)(bn + row) * K + kt + c * 8, baseB + i16 * 16);
    }
  };

  const int T = K / 32;
  stage(0, 0);
  stage(1, 1);
  stage(2, 2);

  // read-side swizzled slot: ((lg + (row>>1)) & 3); (row>>1)&3 == (lr>>1)&3
  // since wm, wn, mt*16 are all multiples of 8.
  const int slotA = ((lg + (lr >> 1)) & 3) * 8;  // u16 offset within row

  for (int t = 0; t < T; ++t) {
    const int rem = T - 1 - t;
    if (rem >= 2)
      asm volatile("s_waitcnt vmcnt(8)" ::: "memory");
    else if (rem == 1)
      asm volatile("s_waitcnt vmcnt(4)" ::: "memory");
    else
      asm volatile("s_waitcnt vmcnt(0)" ::: "memory");
    __builtin_amdgcn_s_barrier();

    const u16* cA = lA + (t % 3) * BM * 32;
    const u16* cB = lB + (t % 3) * BN * 32;
    bf16x8 af[MREP], bfr[NREP];
#pragma unroll
    for (int mt = 0; mt < MREP; ++mt)
      af[mt] = *(const bf16x8*)&cA[(wm + mt * 16 + lr) * 32 + slotA];
#pragma unroll
    for (int nt = 0; nt < NREP; ++nt)
      bfr[nt] = *(const bf16x8*)&cB[(wn + nt * 16 + lr) * 32 + slotA];
#pragma unroll
    for (int mt = 0; mt < MREP; ++mt)
#pragma unroll
      for (int nt = 0; nt < NREP; ++nt)
        acc[mt][nt] = mfma16(af[mt], bfr[nt], acc[mt][nt]);

    __builtin_amdgcn_sched_barrier(0);
    __builtin_amdgcn_s_barrier();
    if (t + 3 < T) stage(t % 3, t + 3);
  }

#pragma unroll
  for (int nt = 0; nt < NREP; ++nt) {
    int col = bn + wn + nt * 16 + lr;
    float bv = bias[col];
#pragma unroll
    for (int mt = 0; mt < MREP; ++mt) {
#pragma unroll
      for (int r = 0; r < 4; ++r) {
        int row = bm + wm + mt * 16 + lg * 4 + r;
        float val = acc[mt][nt][r] + bv;
        if (MODE == 0) {
          Cout[(size_t)row * N + col] = val;
        } else {
          __bf16 bx = (__bf16)val;
          int b = row >> 11, s = row & 2047;
          int third = col >> 10, hd = col & 1023;
          int h = hd >> 6, d = hd & 63;
          if (third == 0) {
            qb[(size_t)row * 1024 + hd] = bx;
          } else {
            int bh = b * 16 + h, t2 = s >> 6, sr = s & 63;
            size_t tb = ((size_t)(bh * 32 + t2)) * 4096;
            if (third == 1)
              kp[tb + (sr >> 4) * 1024 + (d >> 5) * 512 + ((d >> 3) & 3) * 128 +
                 (sr & 15) * 8 + (d & 7)] = bx;
            else
              vp[tb + (d >> 4) * 1024 + (sr >> 5) * 512 + ((sr >> 3) & 3) * 128 +
                 (d & 15) * 8 + (sr & 7)] = bx;
          }
        }
      }
    }
  }
}

// ---------------- fused causal+ALiBi flash attention ----------------
// 4096 independent 1-wave blocks; K/V fragment-linear packed tiles in L2.
__global__ __launch_bounds__(64, 4) void attn_kernel(
    const __bf16* __restrict__ qb, const __bf16* __restrict__ kp,
    const __bf16* __restrict__ vp, __bf16* __restrict__ aout) {
  __shared__ __bf16 p_lds[16][72];
  const int lane = threadIdx.x & 63;
  const int lr = lane & 15;
  const int lg = lane >> 4;

  const int lid = blockIdx.x;
  const int xcd = lid & 7;
  const int rest = lid >> 3;
  const int bh = xcd * 4 + (rest & 3);
  const int a16 = 127 - (rest >> 2);
  const int b = bh >> 4, h = bh & 15;
  const int qr0 = a16 * 16;
  const int ntl = (a16 >> 2) + 1;

  const float LOG2E = 1.4426950408889634f;
  const float c1 = 0.125f * LOG2E;
  const float c2 = exp2f(-(float)(h + 1) * 0.5f) * LOG2E;

  bf16x8 ones;
#pragma unroll
  for (int j = 0; j < 8; ++j) ones[j] = (__bf16)1.0f;

  const u16* ktiles = (const u16*)kp + (size_t)bh * 32 * 4096;
  const u16* vtiles = (const u16*)vp + (size_t)bh * 32 * 4096;

  const __bf16* qrow = qb + (size_t)(b * 2048 + qr0 + lr) * 1024 + h * 64;
  bf16x8 qf0 = *(const bf16x8*)(qrow + lg * 8);
  bf16x8 qf1 = *(const bf16x8*)(qrow + 32 + lg * 8);

  float m[4], l[4], cq[4];
  f32x4 o[4];
#pragma unroll
  for (int r = 0; r < 4; ++r) {
    m[r] = 0.f;
    l[r] = 0.f;
    cq[r] = c2 * (float)(qr0 + lg * 4 + r);
  }
#pragma unroll
  for (int dt = 0; dt < 4; ++dt) o[dt] = (f32x4){0.f, 0.f, 0.f, 0.f};

  for (int t = 0; t < ntl; ++t) {
    const u16* kb = ktiles + (size_t)t * 4096;
    const u16* vb = vtiles + (size_t)t * 4096;
    const int kv = t * 64;
    const bool last = (t == ntl - 1);

    bf16x8 ka[8], va[8];
#pragma unroll
    for (int j = 0; j < 8; ++j)
      ka[j] = *(const bf16x8*)(kb + j * 512 + lane * 8);
#pragma unroll
    for (int j = 0; j < 8; ++j)
      va[j] = *(const bf16x8*)(vb + j * 512 + lane * 8);

    f32x4 s[4];
#pragma unroll
    for (int nt = 0; nt < 4; ++nt) {
      f32x4 tt = (f32x4){0.f, 0.f, 0.f, 0.f};
      tt = mfma16(qf0, ka[nt * 2], tt);
      tt = mfma16(qf1, ka[nt * 2 + 1], tt);
      s[nt] = tt;
    }

#pragma unroll
    for (int nt = 0; nt < 4; ++nt) {
      float bnt = c2 * (float)(kv + nt * 16 + lr);
#pragma unroll
      for (int r = 0; r < 4; ++r)
        s[nt][r] = __builtin_fmaf(s[nt][r], c1, bnt - cq[r]);
    }
    if (last) {
#pragma unroll
      for (int nt = 0; nt < 4; ++nt) {
        float kf = (float)(kv + nt * 16 + lr);
#pragma unroll
        for (int r = 0; r < 4; ++r) {
          float qi = (float)(qr0 + lg * 4 + r);
          if (kf > qi) s[nt][r] = -1e30f;
        }
      }
    }

    float pm[4];
#pragma unroll
    for (int r = 0; r < 4; ++r)
      pm[r] = fmaxf(fmaxf(s[0][r], s[1][r]), fmaxf(s[2][r], s[3][r]));
    bool ok = (pm[0] <= m[0] + 8.f) && (pm[1] <= m[1] + 8.f) &&
              (pm[2] <= m[2] + 8.f) && (pm[3] <= m[3] + 8.f);
    if (!__all(ok)) {
#pragma unroll
      for (int r = 0; r < 4; ++r)
#pragma unroll
        for (int d = 1; d < 16; d <<= 1)
          pm[r] = fmaxf(pm[r], __shfl_xor(pm[r], d));
#pragma unroll
      for (int r = 0; r < 4; ++r) {
        float mn = fmaxf(m[r], pm[r]);
        float fac = __builtin_amdgcn_exp2f(m[r] - mn);
        m[r] = mn;
        l[r] *= fac;
#pragma unroll
        for (int dt = 0; dt < 4; ++dt) o[dt][r] *= fac;
      }
    }

#pragma unroll
    for (int nt = 0; nt < 4; ++nt)
#pragma unroll
      for (int r = 0; r < 4; ++r) {
        float e = __builtin_amdgcn_exp2f(s[nt][r] - m[r]);
        p_lds[lg * 4 + r][nt * 16 + lr] = (__bf16)e;
      }

    bf16x8 pa0 = *(const bf16x8*)&p_lds[lr][lg * 8];
    bf16x8 pa1 = *(const bf16x8*)&p_lds[lr][32 + lg * 8];

    {
      f32x4 tt = (f32x4){0.f, 0.f, 0.f, 0.f};
      tt = mfma16(pa0, ones, tt);
      tt = mfma16(pa1, ones, tt);
#pragma unroll
      for (int r = 0; r < 4; ++r) l[r] += tt[r];
    }

#pragma unroll
    for (int dt = 0; dt < 4; ++dt) {
      o[dt] = mfma16(pa0, va[dt * 2], o[dt]);
      o[dt] = mfma16(pa1, va[dt * 2 + 1], o[dt]);
    }
  }

#pragma unroll
  for (int dt = 0; dt < 4; ++dt)
#pragma unroll
    for (int r = 0; r < 4; ++r) {
      float val = o[dt][r] / l[r];
      aout[(size_t)(b * 2048 + qr0 + lg * 4 + r) * 1024 + h * 64 + dt * 16 + lr] =
          (__bf16)val;
    }
}

extern "C" void kernel_launch(void* const* d_in, const int* in_sizes, int n_in,
                              void* d_out, int out_size, void* d_ws, size_t ws_size,
                              hipStream_t stream) {
  (void)in_sizes; (void)n_in; (void)out_size; (void)ws_size;
  const float* x = (const float*)d_in[0];
  const float* Wp = (const float*)d_in[1];
  const float* bp = (const float*)d_in[2];
  const float* Wo = (const float*)d_in[3];
  const float* bo = (const float*)d_in[4];
  float* out = (float*)d_out;

  char* ws = (char*)d_ws;
  u16* xb  = (u16*)(ws);                        // 8 MB  x bf16 [4096,1024]
  u16* wpb = (u16*)(ws + (size_t)(8u << 20));   // 6 MB  W_packed bf16
  u16* wob = (u16*)(ws + (size_t)(14u << 20));  // 2 MB  W_out bf16
  u16* qbp = (u16*)(ws + (size_t)(16u << 20));  // 8 MB  Q [4096,1024]
  u16* kpp = (u16*)(ws + (size_t)(24u << 20));  // 8 MB  K fragment tiles
  u16* vpp = (u16*)(ws + (size_t)(32u << 20));  // 8 MB  V fragment tiles
  u16* ab  = xb;  // attention output reuses x_bf16 space

  cvt3_kernel<<<2048, 256, 0, stream>>>(x, Wp, Wo, (__bf16*)xb);
  // gemm1: 128x128, grid 32*24 = 768 blocks
  gemm_bt<128, 128, 1><<<768, 256, 0, stream>>>(
      xb, wpb, bp, nullptr, (__bf16*)qbp, (__bf16*)kpp, (__bf16*)vpp,
      4096, 3072, 1024, 32);
  attn_kernel<<<4096, 64, 0, stream>>>(
      (const __bf16*)qbp, (const __bf16*)kpp, (const __bf16*)vpp, (__bf16*)ab);
  // gemm2: 128x128, grid 32*8 = 256 blocks
  gemm_bt<128, 128, 0><<<256, 256, 0, stream>>>(
      ab, wob, bo, out, nullptr, nullptr, nullptr, 4096, 1024, 1024, 32);
}